// Round 5
// baseline (186.072 us; speedup 1.0000x reference)
//
#include <hip/hip_runtime.h>
#include <stdint.h>

typedef __bf16 bf16_t;
typedef bf16_t bf16x8 __attribute__((ext_vector_type(8)));
typedef float floatx4 __attribute__((ext_vector_type(4)));

__device__ __forceinline__ uint16_t f2bf(float f){
  union { float f; uint32_t i; } c; c.f = f;
  uint32_t r = (c.i + 0x7FFFu + ((c.i >> 16) & 1u)) >> 16;
  return (uint16_t)r;
}
__device__ __forceinline__ float bflo(uint32_t u){
  union { uint32_t i; float f; } c; c.i = u << 16; return c.f;
}
__device__ __forceinline__ float bfhi(uint32_t u){
  union { uint32_t i; float f; } c; c.i = u & 0xffff0000u; return c.f;
}

// ---------- elementwise fp32 -> bf16 convert, 8 elems/thread ----------
__global__ __launch_bounds__(256) void convert_f32_bf16(
    const float* __restrict__ src, uint16_t* __restrict__ dst)
{
  int idx = blockIdx.x * 256 + threadIdx.x;   // one uint4 (8 bf16) per thread
  const float4* s = (const float4*)src + (size_t)idx * 2;
  float4 a = s[0], b = s[1];
  uint4 pk;
  pk.x = (uint32_t)f2bf(a.x) | ((uint32_t)f2bf(a.y) << 16);
  pk.y = (uint32_t)f2bf(a.z) | ((uint32_t)f2bf(a.w) << 16);
  pk.z = (uint32_t)f2bf(b.x) | ((uint32_t)f2bf(b.y) << 16);
  pk.w = (uint32_t)f2bf(b.z) | ((uint32_t)f2bf(b.w) << 16);
  ((uint4*)dst)[idx] = pk;
}

// ---------- transpose + convert: dst[n*K+k] (bf16) = src[k*N+n] (fp32) ----------
__global__ __launch_bounds__(256) void transpose_f32_bf16(
    const float* __restrict__ src, uint16_t* __restrict__ dst, int K, int N)
{
  __shared__ uint16_t tile[64][65];
  int k0 = blockIdx.x * 64, n0 = blockIdx.y * 64;
  for (int idx = threadIdx.x; idx < 64 * 64; idx += 256){
    int r = idx >> 6, c = idx & 63;
    tile[r][c] = f2bf(src[(k0 + r) * N + n0 + c]);
  }
  __syncthreads();
  for (int idx = threadIdx.x; idx < 64 * 64; idx += 256){
    int r = idx >> 6, c = idx & 63;
    dst[(n0 + r) * K + k0 + c] = tile[c][r];
  }
}

// ---------- GEMM: C[M,N] = A[M,256] (bf16) * Bt[N,256]^T (bf16) + bias (fp32) ----------
#define KDIM 256
#define KHALF 128
#define KP 136  // LDS row stride (bf16 elems): 16B-aligned rows, 2-way-free bank aliasing

template<int OUTF32>
__global__ __launch_bounds__(256) void gemm_bt_bias(
    const uint16_t* __restrict__ A,
    const uint16_t* __restrict__ Bt,
    const float* __restrict__ bias,
    void* __restrict__ Cv,
    int N)
{
  __shared__ uint16_t Al[64 * KP];
  __shared__ uint16_t Bl[64 * KP];
  const int m0 = blockIdx.x * 64, n0 = blockIdx.y * 64;
  const int t = threadIdx.x;
  const int lane = t & 63;
  const int wave = t >> 6;
  const int wm = (wave & 1) * 32, wn = (wave >> 1) * 32;
  const int fr = lane & 15;        // fragment row (m or n)
  const int q8 = (lane >> 4) * 8;  // k sub-offset

  floatx4 acc00 = {0.f,0.f,0.f,0.f}, acc01 = {0.f,0.f,0.f,0.f};
  floatx4 acc10 = {0.f,0.f,0.f,0.f}, acc11 = {0.f,0.f,0.f,0.f};

  const int sr = t >> 2;          // staging row 0..63
  const int sc = (t & 3) * 32;    // staging col base within 128

  for (int ko = 0; ko < 2; ko++){
    if (ko) __syncthreads();
    const uint16_t* ga = A  + (m0 + sr) * KDIM + ko * KHALF + sc;
    const uint16_t* gb = Bt + (n0 + sr) * KDIM + ko * KHALF + sc;
    uint16_t* la = Al + sr * KP + sc;
    uint16_t* lb = Bl + sr * KP + sc;
    #pragma unroll
    for (int ii = 0; ii < 32; ii += 8){
      *(bf16x8*)(la + ii) = *(const bf16x8*)(ga + ii);
      *(bf16x8*)(lb + ii) = *(const bf16x8*)(gb + ii);
    }
    __syncthreads();
    #pragma unroll
    for (int kk = 0; kk < KHALF; kk += 32){
      bf16x8 a0 = *(const bf16x8*)(Al + (wm + fr)      * KP + kk + q8);
      bf16x8 a1 = *(const bf16x8*)(Al + (wm + 16 + fr) * KP + kk + q8);
      bf16x8 b0 = *(const bf16x8*)(Bl + (wn + fr)      * KP + kk + q8);
      bf16x8 b1 = *(const bf16x8*)(Bl + (wn + 16 + fr) * KP + kk + q8);
      acc00 = __builtin_amdgcn_mfma_f32_16x16x32_bf16(a0, b0, acc00, 0, 0, 0);
      acc01 = __builtin_amdgcn_mfma_f32_16x16x32_bf16(a0, b1, acc01, 0, 0, 0);
      acc10 = __builtin_amdgcn_mfma_f32_16x16x32_bf16(a1, b0, acc10, 0, 0, 0);
      acc11 = __builtin_amdgcn_mfma_f32_16x16x32_bf16(a1, b1, acc11, 0, 0, 0);
    }
  }

  // epilogue: C/D layout col=lane&15, row=(lane>>4)*4+r  [verified m89/m91]
  const int ccol = lane & 15;
  const int crow = (lane >> 4) * 4;
  float bv0 = bias[n0 + wn + ccol];
  float bv1 = bias[n0 + wn + 16 + ccol];
  #pragma unroll
  for (int r2 = 0; r2 < 4; r2++){
    int rA = m0 + wm + crow + r2;
    int rB = rA + 16;
    if (OUTF32){
      float* C = (float*)Cv;
      C[rA * N + n0 + wn + ccol]      = acc00[r2] + bv0;
      C[rA * N + n0 + wn + 16 + ccol] = acc01[r2] + bv1;
      C[rB * N + n0 + wn + ccol]      = acc10[r2] + bv0;
      C[rB * N + n0 + wn + 16 + ccol] = acc11[r2] + bv1;
    } else {
      uint16_t* C = (uint16_t*)Cv;
      C[rA * N + n0 + wn + ccol]      = f2bf(acc00[r2] + bv0);
      C[rA * N + n0 + wn + 16 + ccol] = f2bf(acc01[r2] + bv1);
      C[rB * N + n0 + wn + ccol]      = f2bf(acc10[r2] + bv0);
      C[rB * N + n0 + wn + 16 + ccol] = f2bf(acc11[r2] + bv1);
    }
  }
}

// ---------- NATTEN attention v3: 8 lanes per query ----------
// Block = 256 threads = 4 waves; wave = 8 queries x 8 lanes; block tile = 4(i) x 8(j).
// Lane owns 4 of 32 head-dims; QK partials reduced via shfl_xor(1,2,4);
// 49 logits distributed 7/lane (owner = key%8); AV weights via shfl broadcast.
__global__ __launch_bounds__(256, 6) void natten_kernel(
    const uint16_t* __restrict__ qkv,   // [6272][768] bf16: q|k|v each [8 heads][32]
    const float* __restrict__ rpb0,     // [4][13][13] fp32
    const float* __restrict__ rpb1,     // [4][13][13] fp32
    uint16_t* __restrict__ attn_out)    // [6272][256] bf16
{
  const int t = threadIdx.x;
  const int c  = t & 7;                 // dim-group 0..7 (4 dims each)
  const int qi = t >> 3;                // query within 4x8 tile, 0..31
  const int j = blockIdx.x * 8 + (qi & 7);
  const int i = blockIdx.y * 4 + (qi >> 3);
  const int z = blockIdx.z;             // b*8 + h
  const int b = z >> 3, h = z & 7;
  const int split = h >> 2;
  const int dil = split + 1;            // DIL = (1, 2)
  const float* rpb = (split ? rpb1 : rpb0) + (h & 3) * 169;

  const int ri = i % dil, pi = i / dil;
  const int rj = j % dil, pj = j / dil;
  const int Lri = (56 - ri + dil - 1) / dil;
  const int Lrj = (56 - rj + dil - 1) / dil;
  const int psi = min(max(pi - 3, 0), Lri - 7);
  const int psj = min(max(pj - 3, 0), Lrj - 7);
  const int bi0 = psi - pi + 6, bj0 = psj - pj + 6;
  const int ni0 = psi * dil + ri, nj0 = psj * dil + rj;

  const int tok = (b * 56 + i) * 56 + j;
  const float scale = 0.17677669529663687f;  // 32^-0.5

  float qv[4];
  {
    uint2 u = *(const uint2*)(qkv + (size_t)tok * 768 + h * 32 + c * 4);
    qv[0] = bflo(u.x) * scale; qv[1] = bfhi(u.x) * scale;
    qv[2] = bflo(u.y) * scale; qv[3] = bfhi(u.y) * scale;
  }

  float lgl[7];
  lgl[6] = -1e30f;   // only lane c==0 owns key 48; others keep -inf
  #pragma unroll
  for (int ai = 0; ai < 7; ai++){
    int rowb = (b * 56 + ni0 + ai * dil) * 56;
    int rpi = (bi0 + ai) * 13 + bj0;
    #pragma unroll
    for (int aj = 0; aj < 7; aj++){
      const int a = ai * 7 + aj;
      int tk = rowb + nj0 + aj * dil;
      uint2 u = *(const uint2*)(qkv + (size_t)tk * 768 + 256 + h * 32 + c * 4);
      float d = qv[0] * bflo(u.x) + qv[1] * bfhi(u.x)
              + qv[2] * bflo(u.y) + qv[3] * bfhi(u.y);
      d += __shfl_xor(d, 1);
      d += __shfl_xor(d, 2);
      d += __shfl_xor(d, 4);
      d += rpb[rpi + aj];
      if ((a & 7) == c) lgl[a >> 3] = d;   // predicated static-index store
    }
  }

  // distributed softmax over the 8-lane group
  float mx = lgl[0];
  #pragma unroll
  for (int s = 1; s < 7; s++) mx = fmaxf(mx, lgl[s]);
  mx = fmaxf(mx, __shfl_xor(mx, 1));
  mx = fmaxf(mx, __shfl_xor(mx, 2));
  mx = fmaxf(mx, __shfl_xor(mx, 4));
  float ssum = 0.f;
  #pragma unroll
  for (int s = 0; s < 7; s++){
    float e = __expf(lgl[s] - mx);   // -1e30 slot -> exp underflows to 0
    lgl[s] = e;
    ssum += e;
  }
  ssum += __shfl_xor(ssum, 1);
  ssum += __shfl_xor(ssum, 2);
  ssum += __shfl_xor(ssum, 4);
  float inv = 1.0f / ssum;

  float ov[4];
  #pragma unroll
  for (int d = 0; d < 4; d++) ov[d] = 0.f;

  const int lane8 = t & 56;   // (lane & ~7) within wave
  #pragma unroll
  for (int ai = 0; ai < 7; ai++){
    int rowb = (b * 56 + ni0 + ai * dil) * 56;
    #pragma unroll
    for (int aj = 0; aj < 7; aj++){
      const int a = ai * 7 + aj;
      int tk = rowb + nj0 + aj * dil;
      uint2 u = *(const uint2*)(qkv + (size_t)tk * 768 + 512 + h * 32 + c * 4);
      float w = __shfl(lgl[a >> 3], lane8 | (a & 7)) * inv;
      ov[0] += w * bflo(u.x); ov[1] += w * bfhi(u.x);
      ov[2] += w * bflo(u.y); ov[3] += w * bfhi(u.y);
    }
  }

  uint2 pk;
  pk.x = (uint32_t)f2bf(ov[0]) | ((uint32_t)f2bf(ov[1]) << 16);
  pk.y = (uint32_t)f2bf(ov[2]) | ((uint32_t)f2bf(ov[3]) << 16);
  *(uint2*)(attn_out + (size_t)tok * 256 + h * 32 + c * 4) = pk;
}

extern "C" void kernel_launch(void* const* d_in, const int* in_sizes, int n_in,
                              void* d_out, int out_size, void* d_ws, size_t ws_size,
                              hipStream_t stream)
{
  (void)in_sizes; (void)n_in; (void)out_size; (void)ws_size;
  const float* x      = (const float*)d_in[0];   // [2,56,56,256]
  const float* w_qkv  = (const float*)d_in[1];   // [256,768]
  const float* b_qkv  = (const float*)d_in[2];   // [768]
  const float* w_proj = (const float*)d_in[3];   // [256,256]
  const float* b_proj = (const float*)d_in[4];   // [256]
  const float* rpb0   = (const float*)d_in[5];   // [4,13,13]
  const float* rpb1   = (const float*)d_in[6];   // [4,13,13]
  float* out = (float*)d_out;                    // [2,56,56,256] fp32

  // ws layout (bf16 elems): wqkvT | wprojT | xb | qkv | attn  => ~15.8 MB
  uint16_t* wqkvT  = (uint16_t*)d_ws;                    // 768*256
  uint16_t* wprojT = wqkvT + 768 * 256;                  // 256*256
  uint16_t* xb     = wprojT + 256 * 256;                 // 6272*256
  uint16_t* qkv    = xb + (size_t)6272 * 256;            // 6272*768
  uint16_t* attn   = qkv + (size_t)6272 * 768;           // 6272*256

  convert_f32_bf16<<<dim3(784), 256, 0, stream>>>(x, xb);
  transpose_f32_bf16<<<dim3(4, 12), 256, 0, stream>>>(w_qkv, wqkvT, 256, 768);
  transpose_f32_bf16<<<dim3(4, 4),  256, 0, stream>>>(w_proj, wprojT, 256, 256);
  gemm_bt_bias<0><<<dim3(98, 12), 256, 0, stream>>>(xb, wqkvT, b_qkv, qkv, 768);
  natten_kernel<<<dim3(7, 14, 16), 256, 0, stream>>>(qkv, rpb0, rpb1, attn);
  gemm_bt_bias<1><<<dim3(98, 4), 256, 0, stream>>>(attn, wprojT, b_proj, out, 256);
}

// Round 7
// 127.503 us; speedup vs baseline: 1.4594x; 1.4594x over previous
//
#include <hip/hip_runtime.h>
#include <stdint.h>

typedef __bf16 bf16_t;
typedef bf16_t bf16x8 __attribute__((ext_vector_type(8)));
typedef float floatx4 __attribute__((ext_vector_type(4)));

#define HW 56
#define NTOK 6272   // 2*56*56

__device__ __forceinline__ uint16_t f2bf(float f){
  union { float f; uint32_t i; } c; c.f = f;
  uint32_t r = (c.i + 0x7FFFu + ((c.i >> 16) & 1u)) >> 16;
  return (uint16_t)r;
}
__device__ __forceinline__ float bflo(uint32_t u){
  union { uint32_t i; float f; } c; c.i = u << 16; return c.f;
}
__device__ __forceinline__ float bfhi(uint32_t u){
  union { uint32_t i; float f; } c; c.i = u & 0xffff0000u; return c.f;
}

// ---------- elementwise fp32 -> bf16 convert, 8 elems/thread ----------
__global__ __launch_bounds__(256) void convert_f32_bf16(
    const float* __restrict__ src, uint16_t* __restrict__ dst)
{
  int idx = blockIdx.x * 256 + threadIdx.x;
  const float4* s = (const float4*)src + (size_t)idx * 2;
  float4 a = s[0], b = s[1];
  uint4 pk;
  pk.x = (uint32_t)f2bf(a.x) | ((uint32_t)f2bf(a.y) << 16);
  pk.y = (uint32_t)f2bf(a.z) | ((uint32_t)f2bf(a.w) << 16);
  pk.z = (uint32_t)f2bf(b.x) | ((uint32_t)f2bf(b.y) << 16);
  pk.w = (uint32_t)f2bf(b.z) | ((uint32_t)f2bf(b.w) << 16);
  ((uint4*)dst)[idx] = pk;
}

// ---------- transpose + convert: dst[n*K+k] (bf16) = src[k*N+n] (fp32) ----------
__global__ __launch_bounds__(256) void transpose_f32_bf16(
    const float* __restrict__ src, uint16_t* __restrict__ dst, int K, int N)
{
  __shared__ uint16_t tile[64][65];
  int k0 = blockIdx.x * 64, n0 = blockIdx.y * 64;
  for (int idx = threadIdx.x; idx < 64 * 64; idx += 256){
    int r = idx >> 6, c = idx & 63;
    tile[r][c] = f2bf(src[(k0 + r) * N + n0 + c]);
  }
  __syncthreads();
  for (int idx = threadIdx.x; idx < 64 * 64; idx += 256){
    int r = idx >> 6, c = idx & 63;
    dst[(n0 + r) * K + k0 + c] = tile[c][r];
  }
}

// ---------- GEMM: C[M,N] = A[M,256] (bf16) * Bt[N,256]^T (bf16) + bias (fp32) ----------
// AHM: A is head-major [8][NTOK][32] (attn output layout); else row-major [M][256]
#define KDIM 256
#define KHALF 128
#define KP 136

template<int OUTF32, int AHM>
__global__ __launch_bounds__(256) void gemm_bt_bias(
    const uint16_t* __restrict__ A,
    const uint16_t* __restrict__ Bt,
    const float* __restrict__ bias,
    void* __restrict__ Cv,
    int N)
{
  __shared__ uint16_t Al[64 * KP];
  __shared__ uint16_t Bl[64 * KP];
  const int m0 = blockIdx.x * 64, n0 = blockIdx.y * 64;
  const int t = threadIdx.x;
  const int lane = t & 63;
  const int wave = t >> 6;
  const int wm = (wave & 1) * 32, wn = (wave >> 1) * 32;
  const int fr = lane & 15;
  const int q8 = (lane >> 4) * 8;

  floatx4 acc00 = {0.f,0.f,0.f,0.f}, acc01 = {0.f,0.f,0.f,0.f};
  floatx4 acc10 = {0.f,0.f,0.f,0.f}, acc11 = {0.f,0.f,0.f,0.f};

  const int sr = t >> 2;          // staging row 0..63
  const int sc = (t & 3) * 32;    // staging col base within 128 (multiple of 32)

  for (int ko = 0; ko < 2; ko++){
    if (ko) __syncthreads();
    const uint16_t* ga;
    if (AHM){
      int dim0 = ko * KHALF + sc;                    // multiple of 32 -> one head plane
      ga = A + (size_t)(dim0 >> 5) * (NTOK * 32) + (m0 + sr) * 32;
    } else {
      ga = A + (m0 + sr) * KDIM + ko * KHALF + sc;
    }
    const uint16_t* gb = Bt + (n0 + sr) * KDIM + ko * KHALF + sc;
    uint16_t* la = Al + sr * KP + sc;
    uint16_t* lb = Bl + sr * KP + sc;
    #pragma unroll
    for (int ii = 0; ii < 32; ii += 8){
      *(bf16x8*)(la + ii) = *(const bf16x8*)(ga + ii);
      *(bf16x8*)(lb + ii) = *(const bf16x8*)(gb + ii);
    }
    __syncthreads();
    #pragma unroll
    for (int kk = 0; kk < KHALF; kk += 32){
      bf16x8 a0 = *(const bf16x8*)(Al + (wm + fr)      * KP + kk + q8);
      bf16x8 a1 = *(const bf16x8*)(Al + (wm + 16 + fr) * KP + kk + q8);
      bf16x8 b0 = *(const bf16x8*)(Bl + (wn + fr)      * KP + kk + q8);
      bf16x8 b1 = *(const bf16x8*)(Bl + (wn + 16 + fr) * KP + kk + q8);
      acc00 = __builtin_amdgcn_mfma_f32_16x16x32_bf16(a0, b0, acc00, 0, 0, 0);
      acc01 = __builtin_amdgcn_mfma_f32_16x16x32_bf16(a0, b1, acc01, 0, 0, 0);
      acc10 = __builtin_amdgcn_mfma_f32_16x16x32_bf16(a1, b0, acc10, 0, 0, 0);
      acc11 = __builtin_amdgcn_mfma_f32_16x16x32_bf16(a1, b1, acc11, 0, 0, 0);
    }
  }

  const int ccol = lane & 15;
  const int crow = (lane >> 4) * 4;
  float bv0 = bias[n0 + wn + ccol];
  float bv1 = bias[n0 + wn + 16 + ccol];
  #pragma unroll
  for (int r2 = 0; r2 < 4; r2++){
    int rA = m0 + wm + crow + r2;
    int rB = rA + 16;
    if (OUTF32){
      float* C = (float*)Cv;
      C[rA * N + n0 + wn + ccol]      = acc00[r2] + bv0;
      C[rA * N + n0 + wn + 16 + ccol] = acc01[r2] + bv1;
      C[rB * N + n0 + wn + ccol]      = acc10[r2] + bv0;
      C[rB * N + n0 + wn + 16 + ccol] = acc11[r2] + bv1;
    } else {
      uint16_t* C = (uint16_t*)Cv;
      C[rA * N + n0 + wn + ccol]      = f2bf(acc00[r2] + bv0);
      C[rA * N + n0 + wn + 16 + ccol] = f2bf(acc01[r2] + bv1);
      C[rB * N + n0 + wn + ccol]      = f2bf(acc10[r2] + bv0);
      C[rB * N + n0 + wn + 16 + ccol] = f2bf(acc11[r2] + bv1);
    }
  }
}

// ---------- NATTEN attention v4.1: LDS-staged K/V tile ----------
// Block = 256 thr = one (b,h, 8x8 query tile). K/V neighborhood window (<=20x20
// tokens x 32 dims) staged to LDS. SLP=40 elems (80 B) keeps every b128 LDS
// access 16B-aligned (SLP=34 in v4 was the misaligned-DS crash). Compute:
// 4 lanes/query, shfl reduce, 13 logits/lane. Output head-major [8][NTOK][32].
#define WIN 20
#define SLP 40   // padded slice stride (bf16 elems); 80 B = multiple of 16 B

__global__ __launch_bounds__(256, 2) void natten_kernel(
    const uint16_t* __restrict__ qkv,   // [NTOK][768]
    const float* __restrict__ rpb0,     // [4][13][13]
    const float* __restrict__ rpb1,
    uint16_t* __restrict__ attnH)       // [8][NTOK][32]
{
  __shared__ uint16_t KS[400 * SLP];
  __shared__ uint16_t VS[400 * SLP];
  __shared__ float RPB[169];

  const int t = threadIdx.x;
  const int z = blockIdx.x;             // b*8 + h
  const int b = z >> 3, h = z & 7;
  const int j0 = blockIdx.y * 8, i0 = blockIdx.z * 8;
  const int split = h >> 2;
  const int dil = split + 1;
  const float* rpb = (split ? rpb1 : rpb0) + (h & 3) * 169;
  if (t < 169) RPB[t] = rpb[t];

  const int r0 = max(0, i0 - 3 * dil);
  const int c0 = max(0, j0 - 3 * dil);
  const int R  = min(55, i0 + 7 + 3 * dil) - r0 + 1;   // <= 20
  const int C  = min(55, j0 + 7 + 3 * dil) - c0 + 1;   // <= 20

  // stage K/V: R x WIN token slices (col clamp -> harmless dups, never read)
  const int nchunk = R * WIN * 4;       // 16B chunks per array
  for (int ch = t; ch < nchunk; ch += 256){
    int tok = ch >> 2, q = ch & 3;
    int tr = tok / WIN;
    int tc = tok - tr * WIN; tc = min(tc, C - 1);
    const uint16_t* src = qkv + (size_t)((b * HW + r0 + tr) * HW + c0 + tc) * 768
                          + 256 + h * 32 + q * 8;
    int lds = tok * SLP + q * 8;
    *(bf16x8*)(KS + lds) = *(const bf16x8*)(src);
    *(bf16x8*)(VS + lds) = *(const bf16x8*)(src + 256);
  }
  __syncthreads();

  const int c  = t & 3;                 // dim-group (8 dims)
  const int qi = t >> 2;                // query 0..63
  const int j = j0 + (qi & 7);
  const int i = i0 + (qi >> 3);

  const int ri = i % dil, pi = i / dil;
  const int rj = j % dil, pj = j / dil;
  const int Lri = (HW - ri + dil - 1) / dil;
  const int Lrj = (HW - rj + dil - 1) / dil;
  const int psi = min(max(pi - 3, 0), Lri - 7);
  const int psj = min(max(pj - 3, 0), Lrj - 7);
  const int bi0 = psi - pi + 6, bj0 = psj - pj + 6;
  const int ni0 = psi * dil + ri, nj0 = psj * dil + rj;

  const int tok = (b * HW + i) * HW + j;
  const float scale = 0.17677669529663687f;

  float qv[8];
  {
    uint4 u = *(const uint4*)(qkv + (size_t)tok * 768 + h * 32 + c * 8);
    qv[0] = bflo(u.x) * scale; qv[1] = bfhi(u.x) * scale;
    qv[2] = bflo(u.y) * scale; qv[3] = bfhi(u.y) * scale;
    qv[4] = bflo(u.z) * scale; qv[5] = bfhi(u.z) * scale;
    qv[6] = bflo(u.w) * scale; qv[7] = bfhi(u.w) * scale;
  }

  const int lbase = (ni0 - r0) * WIN + (nj0 - c0);
  float lgl[13];
  lgl[12] = -1e30f;
  #pragma unroll
  for (int ai = 0; ai < 7; ai++){
    int lrow = lbase + ai * dil * WIN;
    int rpi = (bi0 + ai) * 13 + bj0;
    #pragma unroll
    for (int aj = 0; aj < 7; aj++){
      const int a = ai * 7 + aj;
      uint4 u = *(const uint4*)(KS + (lrow + aj * dil) * SLP + c * 8);
      float d = qv[0] * bflo(u.x) + qv[1] * bfhi(u.x)
              + qv[2] * bflo(u.y) + qv[3] * bfhi(u.y)
              + qv[4] * bflo(u.z) + qv[5] * bfhi(u.z)
              + qv[6] * bflo(u.w) + qv[7] * bfhi(u.w);
      d += __shfl_xor(d, 1);
      d += __shfl_xor(d, 2);
      d += RPB[rpi + aj];
      if ((a & 3) == c) lgl[a >> 2] = d;
    }
  }

  float mx = lgl[0];
  #pragma unroll
  for (int s = 1; s < 13; s++) mx = fmaxf(mx, lgl[s]);
  mx = fmaxf(mx, __shfl_xor(mx, 1));
  mx = fmaxf(mx, __shfl_xor(mx, 2));
  float ssum = 0.f;
  #pragma unroll
  for (int s = 0; s < 13; s++){
    float e = __expf(lgl[s] - mx);
    lgl[s] = e;
    ssum += e;
  }
  ssum += __shfl_xor(ssum, 1);
  ssum += __shfl_xor(ssum, 2);
  float inv = 1.0f / ssum;

  float ov[8];
  #pragma unroll
  for (int d = 0; d < 8; d++) ov[d] = 0.f;

  const int lane4 = t & 60;
  #pragma unroll
  for (int ai = 0; ai < 7; ai++){
    int lrow = lbase + ai * dil * WIN;
    #pragma unroll
    for (int aj = 0; aj < 7; aj++){
      const int a = ai * 7 + aj;
      uint4 u = *(const uint4*)(VS + (lrow + aj * dil) * SLP + c * 8);
      float w = __shfl(lgl[a >> 2], lane4 | (a & 3)) * inv;
      ov[0] += w * bflo(u.x); ov[1] += w * bfhi(u.x);
      ov[2] += w * bflo(u.y); ov[3] += w * bfhi(u.y);
      ov[4] += w * bflo(u.z); ov[5] += w * bfhi(u.z);
      ov[6] += w * bflo(u.w); ov[7] += w * bfhi(u.w);
    }
  }

  uint4 pk;
  pk.x = (uint32_t)f2bf(ov[0]) | ((uint32_t)f2bf(ov[1]) << 16);
  pk.y = (uint32_t)f2bf(ov[2]) | ((uint32_t)f2bf(ov[3]) << 16);
  pk.z = (uint32_t)f2bf(ov[4]) | ((uint32_t)f2bf(ov[5]) << 16);
  pk.w = (uint32_t)f2bf(ov[6]) | ((uint32_t)f2bf(ov[7]) << 16);
  *(uint4*)(attnH + ((size_t)h * NTOK + tok) * 32 + c * 8) = pk;
}

extern "C" void kernel_launch(void* const* d_in, const int* in_sizes, int n_in,
                              void* d_out, int out_size, void* d_ws, size_t ws_size,
                              hipStream_t stream)
{
  (void)in_sizes; (void)n_in; (void)out_size; (void)ws_size;
  const float* x      = (const float*)d_in[0];
  const float* w_qkv  = (const float*)d_in[1];
  const float* b_qkv  = (const float*)d_in[2];
  const float* w_proj = (const float*)d_in[3];
  const float* b_proj = (const float*)d_in[4];
  const float* rpb0   = (const float*)d_in[5];
  const float* rpb1   = (const float*)d_in[6];
  float* out = (float*)d_out;

  uint16_t* wqkvT  = (uint16_t*)d_ws;                    // 768*256
  uint16_t* wprojT = wqkvT + 768 * 256;                  // 256*256
  uint16_t* xb     = wprojT + 256 * 256;                 // NTOK*256
  uint16_t* qkv    = xb + (size_t)NTOK * 256;            // NTOK*768
  uint16_t* attn   = qkv + (size_t)NTOK * 768;           // 8*NTOK*32 (head-major)

  convert_f32_bf16<<<dim3(784), 256, 0, stream>>>(x, xb);
  transpose_f32_bf16<<<dim3(4, 12), 256, 0, stream>>>(w_qkv, wqkvT, 256, 768);
  transpose_f32_bf16<<<dim3(4, 4),  256, 0, stream>>>(w_proj, wprojT, 256, 256);
  gemm_bt_bias<0,0><<<dim3(98, 12), 256, 0, stream>>>(xb, wqkvT, b_qkv, qkv, 768);
  natten_kernel<<<dim3(16, 7, 7), 256, 0, stream>>>(qkv, rpb0, rpb1, attn);
  gemm_bt_bias<1,1><<<dim3(98, 4), 256, 0, stream>>>(attn, wprojT, b_proj, out, 256);
}

// Round 8
// 117.586 us; speedup vs baseline: 1.5824x; 1.0843x over previous
//
#include <hip/hip_runtime.h>
#include <stdint.h>

typedef __bf16 bf16_t;
typedef bf16_t bf16x8 __attribute__((ext_vector_type(8)));
typedef float floatx4 __attribute__((ext_vector_type(4)));

#define HW 56
#define NTOK 6272   // 2*56*56

__device__ __forceinline__ uint16_t f2bf(float f){
  union { float f; uint32_t i; } c; c.f = f;
  uint32_t r = (c.i + 0x7FFFu + ((c.i >> 16) & 1u)) >> 16;
  return (uint16_t)r;
}
__device__ __forceinline__ float bflo(uint32_t u){
  union { uint32_t i; float f; } c; c.i = u << 16; return c.f;
}
__device__ __forceinline__ float bfhi(uint32_t u){
  union { uint32_t i; float f; } c; c.i = u & 0xffff0000u; return c.f;
}

// ---------- prep: fused x-convert + both weight transposes ----------
// blocks [0,784): convert x (fp32->bf16, 8 elems/thread)
// blocks [784,832): transpose w_qkv (256x768) -> wqkvT (768x256 bf16)
// blocks [832,848): transpose w_proj (256x256) -> wprojT (256x256 bf16)
__global__ __launch_bounds__(256) void prep_kernel(
    const float* __restrict__ x,      uint16_t* __restrict__ xb,
    const float* __restrict__ w_qkv,  uint16_t* __restrict__ wqkvT,
    const float* __restrict__ w_proj, uint16_t* __restrict__ wprojT)
{
  __shared__ uint16_t tile[64][65];
  const int bx = blockIdx.x;
  const int t = threadIdx.x;
  if (bx < 784){
    int idx = bx * 256 + t;
    const float4* s = (const float4*)x + (size_t)idx * 2;
    float4 a = s[0], b = s[1];
    uint4 pk;
    pk.x = (uint32_t)f2bf(a.x) | ((uint32_t)f2bf(a.y) << 16);
    pk.y = (uint32_t)f2bf(a.z) | ((uint32_t)f2bf(a.w) << 16);
    pk.z = (uint32_t)f2bf(b.x) | ((uint32_t)f2bf(b.y) << 16);
    pk.w = (uint32_t)f2bf(b.z) | ((uint32_t)f2bf(b.w) << 16);
    ((uint4*)xb)[idx] = pk;
    return;
  }
  const float* src; uint16_t* dst; int N, q;
  if (bx < 832){ q = bx - 784; src = w_qkv;  dst = wqkvT;  N = 768; }
  else         { q = bx - 832; src = w_proj; dst = wprojT; N = 256; }
  const int k0 = (q & 3) * 64, n0 = (q >> 2) * 64;   // K=256 always
  for (int idx = t; idx < 64 * 64; idx += 256){
    int r = idx >> 6, c = idx & 63;
    tile[r][c] = f2bf(src[(k0 + r) * N + n0 + c]);
  }
  __syncthreads();
  for (int idx = t; idx < 64 * 64; idx += 256){
    int r = idx >> 6, c = idx & 63;
    dst[(n0 + r) * 256 + k0 + c] = tile[c][r];
  }
}

// ---------- GEMM: C[M,N] = A[M,256](bf16) * Bt[N,256]^T(bf16) + bias(fp32) ----------
// Tile 64 x NT (NT=64 or 128). 4 waves: wave w -> rows (w&1)*32, cols (w>>1)*(NT/2).
// AHM: A is head-major [8][NTOK][32]; else row-major [M][256].
#define KDIM 256
#define KHALF 128
#define KP 136

template<int OUTF32, int AHM, int NT>
__global__ __launch_bounds__(256) void gemm_bt_bias(
    const uint16_t* __restrict__ A,
    const uint16_t* __restrict__ Bt,
    const float* __restrict__ bias,
    void* __restrict__ Cv,
    int N)
{
  constexpr int NF = NT / 32;            // B frags per wave (2 or 4)
  __shared__ uint16_t Al[64 * KP];
  __shared__ uint16_t Bl[NT * KP];
  const int m0 = blockIdx.x * 64, n0 = blockIdx.y * NT;
  const int t = threadIdx.x;
  const int lane = t & 63;
  const int wave = t >> 6;
  const int wm = (wave & 1) * 32;
  const int wn = (wave >> 1) * (NF * 16);
  const int fr = lane & 15;
  const int q8 = (lane >> 4) * 8;

  floatx4 acc[2][NF];
  #pragma unroll
  for (int mi = 0; mi < 2; mi++)
    #pragma unroll
    for (int nf = 0; nf < NF; nf++) acc[mi][nf] = (floatx4){0.f,0.f,0.f,0.f};

  constexpr int NCH = (64 + NT) * 16;    // 16B chunks per ko half

  for (int ko = 0; ko < 2; ko++){
    if (ko) __syncthreads();
    #pragma unroll
    for (int ch0 = 0; ch0 < NCH; ch0 += 256){
      int ch = ch0 + t;
      if (ch < 1024){                    // A chunk
        int row = ch >> 4, col = (ch & 15) * 8;
        const uint16_t* ga;
        if (AHM){
          int d0 = ko * KHALF + col;     // chunk stays within one 32-dim head plane
          ga = A + (size_t)(d0 >> 5) * (NTOK * 32) + (m0 + row) * 32 + (d0 & 31);
        } else {
          ga = A + (m0 + row) * KDIM + ko * KHALF + col;
        }
        *(bf16x8*)(Al + row * KP + col) = *(const bf16x8*)ga;
      } else {                           // B chunk
        int idx = ch - 1024;
        int row = idx >> 4, col = (idx & 15) * 8;
        *(bf16x8*)(Bl + row * KP + col) =
            *(const bf16x8*)(Bt + (n0 + row) * KDIM + ko * KHALF + col);
      }
    }
    __syncthreads();
    #pragma unroll
    for (int kk = 0; kk < KHALF; kk += 32){
      bf16x8 a0 = *(const bf16x8*)(Al + (wm + fr)      * KP + kk + q8);
      bf16x8 a1 = *(const bf16x8*)(Al + (wm + 16 + fr) * KP + kk + q8);
      bf16x8 bfrag[NF];
      #pragma unroll
      for (int nf = 0; nf < NF; nf++)
        bfrag[nf] = *(const bf16x8*)(Bl + (wn + nf * 16 + fr) * KP + kk + q8);
      #pragma unroll
      for (int nf = 0; nf < NF; nf++){
        acc[0][nf] = __builtin_amdgcn_mfma_f32_16x16x32_bf16(a0, bfrag[nf], acc[0][nf], 0, 0, 0);
        acc[1][nf] = __builtin_amdgcn_mfma_f32_16x16x32_bf16(a1, bfrag[nf], acc[1][nf], 0, 0, 0);
      }
    }
  }

  // epilogue: C/D layout col=lane&15, row=(lane>>4)*4+r  [verified m89/m91]
  const int ccol = lane & 15;
  const int crow = (lane >> 4) * 4;
  float bv[NF];
  #pragma unroll
  for (int nf = 0; nf < NF; nf++) bv[nf] = bias[n0 + wn + nf * 16 + ccol];
  #pragma unroll
  for (int mi = 0; mi < 2; mi++){
    #pragma unroll
    for (int r2 = 0; r2 < 4; r2++){
      int r = m0 + wm + mi * 16 + crow + r2;
      #pragma unroll
      for (int nf = 0; nf < NF; nf++){
        int cidx = r * N + n0 + wn + nf * 16 + ccol;
        if (OUTF32) ((float*)Cv)[cidx] = acc[mi][nf][r2] + bv[nf];
        else        ((uint16_t*)Cv)[cidx] = f2bf(acc[mi][nf][r2] + bv[nf]);
      }
    }
  }
}

// ---------- NATTEN attention v4.1: LDS-staged K/V tile (unchanged from r7) ----------
#define WIN 20
#define SLP 40   // 80 B slice stride: every b128 LDS access stays 16B-aligned

__global__ __launch_bounds__(256, 2) void natten_kernel(
    const uint16_t* __restrict__ qkv,   // [NTOK][768]
    const float* __restrict__ rpb0,     // [4][13][13]
    const float* __restrict__ rpb1,
    uint16_t* __restrict__ attnH)       // [8][NTOK][32]
{
  __shared__ uint16_t KS[400 * SLP];
  __shared__ uint16_t VS[400 * SLP];
  __shared__ float RPB[169];

  const int t = threadIdx.x;
  const int z = blockIdx.x;             // b*8 + h
  const int b = z >> 3, h = z & 7;
  const int j0 = blockIdx.y * 8, i0 = blockIdx.z * 8;
  const int split = h >> 2;
  const int dil = split + 1;
  const float* rpb = (split ? rpb1 : rpb0) + (h & 3) * 169;
  if (t < 169) RPB[t] = rpb[t];

  const int r0 = max(0, i0 - 3 * dil);
  const int c0 = max(0, j0 - 3 * dil);
  const int R  = min(55, i0 + 7 + 3 * dil) - r0 + 1;   // <= 20
  const int C  = min(55, j0 + 7 + 3 * dil) - c0 + 1;   // <= 20

  const int nchunk = R * WIN * 4;       // 16B chunks per array
  for (int ch = t; ch < nchunk; ch += 256){
    int tok = ch >> 2, q = ch & 3;
    int tr = tok / WIN;
    int tc = tok - tr * WIN; tc = min(tc, C - 1);
    const uint16_t* src = qkv + (size_t)((b * HW + r0 + tr) * HW + c0 + tc) * 768
                          + 256 + h * 32 + q * 8;
    int lds = tok * SLP + q * 8;
    *(bf16x8*)(KS + lds) = *(const bf16x8*)(src);
    *(bf16x8*)(VS + lds) = *(const bf16x8*)(src + 256);
  }
  __syncthreads();

  const int c  = t & 3;
  const int qi = t >> 2;
  const int j = j0 + (qi & 7);
  const int i = i0 + (qi >> 3);

  const int ri = i % dil, pi = i / dil;
  const int rj = j % dil, pj = j / dil;
  const int Lri = (HW - ri + dil - 1) / dil;
  const int Lrj = (HW - rj + dil - 1) / dil;
  const int psi = min(max(pi - 3, 0), Lri - 7);
  const int psj = min(max(pj - 3, 0), Lrj - 7);
  const int bi0 = psi - pi + 6, bj0 = psj - pj + 6;
  const int ni0 = psi * dil + ri, nj0 = psj * dil + rj;

  const int tok = (b * HW + i) * HW + j;
  const float scale = 0.17677669529663687f;

  float qv[8];
  {
    uint4 u = *(const uint4*)(qkv + (size_t)tok * 768 + h * 32 + c * 8);
    qv[0] = bflo(u.x) * scale; qv[1] = bfhi(u.x) * scale;
    qv[2] = bflo(u.y) * scale; qv[3] = bfhi(u.y) * scale;
    qv[4] = bflo(u.z) * scale; qv[5] = bfhi(u.z) * scale;
    qv[6] = bflo(u.w) * scale; qv[7] = bfhi(u.w) * scale;
  }

  const int lbase = (ni0 - r0) * WIN + (nj0 - c0);
  float lgl[13];
  lgl[12] = -1e30f;
  #pragma unroll
  for (int ai = 0; ai < 7; ai++){
    int lrow = lbase + ai * dil * WIN;
    int rpi = (bi0 + ai) * 13 + bj0;
    #pragma unroll
    for (int aj = 0; aj < 7; aj++){
      const int a = ai * 7 + aj;
      uint4 u = *(const uint4*)(KS + (lrow + aj * dil) * SLP + c * 8);
      float d = qv[0] * bflo(u.x) + qv[1] * bfhi(u.x)
              + qv[2] * bflo(u.y) + qv[3] * bfhi(u.y)
              + qv[4] * bflo(u.z) + qv[5] * bfhi(u.z)
              + qv[6] * bflo(u.w) + qv[7] * bfhi(u.w);
      d += __shfl_xor(d, 1);
      d += __shfl_xor(d, 2);
      d += RPB[rpi + aj];
      if ((a & 3) == c) lgl[a >> 2] = d;
    }
  }

  float mx = lgl[0];
  #pragma unroll
  for (int s = 1; s < 13; s++) mx = fmaxf(mx, lgl[s]);
  mx = fmaxf(mx, __shfl_xor(mx, 1));
  mx = fmaxf(mx, __shfl_xor(mx, 2));
  float ssum = 0.f;
  #pragma unroll
  for (int s = 0; s < 13; s++){
    float e = __expf(lgl[s] - mx);
    lgl[s] = e;
    ssum += e;
  }
  ssum += __shfl_xor(ssum, 1);
  ssum += __shfl_xor(ssum, 2);
  float inv = 1.0f / ssum;

  float ov[8];
  #pragma unroll
  for (int d = 0; d < 8; d++) ov[d] = 0.f;

  const int lane4 = t & 60;
  #pragma unroll
  for (int ai = 0; ai < 7; ai++){
    int lrow = lbase + ai * dil * WIN;
    #pragma unroll
    for (int aj = 0; aj < 7; aj++){
      const int a = ai * 7 + aj;
      uint4 u = *(const uint4*)(VS + (lrow + aj * dil) * SLP + c * 8);
      float w = __shfl(lgl[a >> 2], lane4 | (a & 3)) * inv;
      ov[0] += w * bflo(u.x); ov[1] += w * bfhi(u.x);
      ov[2] += w * bflo(u.y); ov[3] += w * bfhi(u.y);
      ov[4] += w * bflo(u.z); ov[5] += w * bfhi(u.z);
      ov[6] += w * bflo(u.w); ov[7] += w * bfhi(u.w);
    }
  }

  uint4 pk;
  pk.x = (uint32_t)f2bf(ov[0]) | ((uint32_t)f2bf(ov[1]) << 16);
  pk.y = (uint32_t)f2bf(ov[2]) | ((uint32_t)f2bf(ov[3]) << 16);
  pk.z = (uint32_t)f2bf(ov[4]) | ((uint32_t)f2bf(ov[5]) << 16);
  pk.w = (uint32_t)f2bf(ov[6]) | ((uint32_t)f2bf(ov[7]) << 16);
  *(uint4*)(attnH + ((size_t)h * NTOK + tok) * 32 + c * 8) = pk;
}

extern "C" void kernel_launch(void* const* d_in, const int* in_sizes, int n_in,
                              void* d_out, int out_size, void* d_ws, size_t ws_size,
                              hipStream_t stream)
{
  (void)in_sizes; (void)n_in; (void)out_size; (void)ws_size;
  const float* x      = (const float*)d_in[0];
  const float* w_qkv  = (const float*)d_in[1];
  const float* b_qkv  = (const float*)d_in[2];
  const float* w_proj = (const float*)d_in[3];
  const float* b_proj = (const float*)d_in[4];
  const float* rpb0   = (const float*)d_in[5];
  const float* rpb1   = (const float*)d_in[6];
  float* out = (float*)d_out;

  uint16_t* wqkvT  = (uint16_t*)d_ws;                    // 768*256
  uint16_t* wprojT = wqkvT + 768 * 256;                  // 256*256
  uint16_t* xb     = wprojT + 256 * 256;                 // NTOK*256
  uint16_t* qkv    = xb + (size_t)NTOK * 256;            // NTOK*768
  uint16_t* attn   = qkv + (size_t)NTOK * 768;           // 8*NTOK*32 (head-major)

  prep_kernel<<<dim3(848), 256, 0, stream>>>(x, xb, w_qkv, wqkvT, w_proj, wprojT);
  gemm_bt_bias<0,0,128><<<dim3(98, 6), 256, 0, stream>>>(xb, wqkvT, b_qkv, qkv, 768);
  natten_kernel<<<dim3(16, 7, 7), 256, 0, stream>>>(qkv, rpb0, rpb1, attn);
  gemm_bt_bias<1,1,64><<<dim3(98, 4), 256, 0, stream>>>(attn, wprojT, b_proj, out, 256);
}